// Round 17
// baseline (259.242 us; speedup 1.0000x reference)
//
#include <hip/hip_runtime.h>

#define NN 100000
#define NE 640000
#define GB1 ((NN + 63) / 64)        // 1563 gemm blocks (64 rows each)
#define EPB ((NE + GB1 - 1) / GB1)  // 410 edges per gemm block (hist tail)
#define PWB 160                     // prepW blocks (40960 elems / 256)
#define ZB  ((2 * NN + 64 + 255) / 256) // zero blocks (degcnt + base_ctr pad)

typedef unsigned int uint32;
typedef unsigned long long uint64;
typedef __attribute__((ext_vector_type(8))) short short8;
typedef __attribute__((ext_vector_type(4))) float f32x4;

static __device__ __forceinline__ ushort f2bf(float f) {
    uint32 u = __float_as_uint(f);
    u = (u + 0x7fffu + ((u >> 16) & 1u)) >> 16;
    return (ushort)u;
}
static __device__ __forceinline__ float bf2f(uint32 bits16) {
    return __uint_as_float(bits16 << 16);
}
static __device__ __forceinline__ uint32 pack2(float a, float b) {
    return (uint32)f2bf(a) | ((uint32)f2bf(b) << 16);
}

// ---------------- prepW (blocks 0..159) + zero degcnt/base_ctr (blocks 160+) ----------------
__global__ void k_prep_zero(const float* __restrict__ W1, const float* __restrict__ W2,
                            const float* __restrict__ W3, ushort* __restrict__ wt1,
                            ushort* __restrict__ wt2, ushort* __restrict__ wt3,
                            int* __restrict__ zbase) {
    const int b = blockIdx.x;
    if (b < PWB) {
        int o = b * 256 + threadIdx.x;
        if (o < 16384) {
            int col = o >> 7, k = o & 127;
            wt1[o] = f2bf(W1[k * 128 + col]);
        } else if (o < 32768) {
            int oo = o - 16384;
            int col = oo >> 7, k = oo & 127;
            wt2[oo] = f2bf(W2[k * 128 + col]);
        } else if (o < 40960) {
            int oo = o - 32768;
            int col = oo >> 7, k = oo & 127;
            wt3[oo] = f2bf(W3[k * 64 + col]);
        }
    } else {
        int i = (b - PWB) * 256 + threadIdx.x;
        if (i < 2 * NN + 64) zbase[i] = 0;   // degcnt (2NN ints) + base_ctr pad
    }
}

// ---------------- GEMM body (R11-proven): H(bf16) = X(f32->bf16) @ Wt(bf16) ----------------
template <int NOUT>
static __device__ __forceinline__ void gemm_body(const float* __restrict__ X,
                                                 const ushort* __restrict__ Wt,
                                                 ushort* __restrict__ H, int N,
                                                 int bid, int tid, char* smem) {
    char* xs = smem;              // [64 rows][128 k] bf16, swizzled
    char* wt = smem + 64 * 256;   // [NOUT cols][128 k] bf16, swizzled
    const int row0 = bid * 64;

    const uint4* Wt4 = reinterpret_cast<const uint4*>(Wt);
#pragma unroll
    for (int i = 0; i < NOUT / 16; ++i) {
        int id = tid + 256 * i;
        int col = id >> 4, c4 = id & 15;
        uint4 v = Wt4[id];
        *reinterpret_cast<uint4*>(wt + col * 256 + ((c4 * 16) ^ ((col & 7) << 4))) = v;
    }
#pragma unroll
    for (int i = 0; i < 8; ++i) {
        int id = tid + 256 * i;
        int r = id >> 5, c4 = id & 31;
        int gr = row0 + r;
        float4 v = make_float4(0.f, 0.f, 0.f, 0.f);
        if (gr < N) v = *reinterpret_cast<const float4*>(&X[(size_t)gr * 128 + c4 * 4]);
        uint2 pk;
        pk.x = pack2(v.x, v.y);
        pk.y = pack2(v.z, v.w);
        *reinterpret_cast<uint2*>(xs + r * 256 + ((c4 * 8) ^ ((r & 7) << 4))) = pk;
    }
    __syncthreads();

    const int w = tid >> 6, lane = tid & 63;
    const int rl = w * 16 + (lane & 15);
    const int kg = lane >> 4;
    f32x4 acc[NOUT / 16];
#pragma unroll
    for (int ct = 0; ct < NOUT / 16; ++ct) acc[ct] = (f32x4){0.f, 0.f, 0.f, 0.f};

#pragma unroll
    for (int ks = 0; ks < 4; ++ks) {
        const int kb = ks * 64 + kg * 16;
        short8 a = *reinterpret_cast<const short8*>(xs + rl * 256 + (kb ^ ((rl & 7) << 4)));
#pragma unroll
        for (int ct = 0; ct < NOUT / 16; ++ct) {
            int col = ct * 16 + (lane & 15);
            short8 bfr = *reinterpret_cast<const short8*>(wt + col * 256 + (kb ^ ((col & 7) << 4)));
            acc[ct] = __builtin_amdgcn_mfma_f32_16x16x32_bf16(a, bfr, acc[ct], 0, 0, 0);
        }
    }
    // C/D layout: col=lane&15, row=(lane>>4)*4+reg (m89-verified)
#pragma unroll
    for (int ct = 0; ct < NOUT / 16; ++ct) {
        int col = ct * 16 + (lane & 15);
#pragma unroll
        for (int r = 0; r < 4; ++r) {
            int gr = row0 + w * 16 + (lane >> 4) * 4 + r;
            if (gr < N) H[(size_t)gr * NOUT + col] = f2bf(acc[ct][r]);
        }
    }
}

// ---------------- merged: gemm1 + per-block hist tail (packed u64 atomic) ----------------
__global__ __launch_bounds__(256) void k_gemm1_hist(const float* __restrict__ X,
                                                    const ushort* __restrict__ Wt1,
                                                    ushort* __restrict__ H, int N,
                                                    const int* __restrict__ dst,
                                                    const float* __restrict__ ew,
                                                    uint64* __restrict__ degcnt) {
    __shared__ char smem[64 * 256 + 128 * 256];
    gemm_body<128>(X, Wt1, H, N, blockIdx.x, threadIdx.x, smem);
    const int ebase = blockIdx.x * EPB;
    const int eend = (ebase + EPB < NE) ? ebase + EPB : NE;
    for (int e = ebase + threadIdx.x; e < eend; e += 256) {
        uint64 pk = (1ull << 44) | (uint64)(ew[e] * 4294967296.0f);
        atomicAdd(&degcnt[dst[e]], pk);
    }
}

// ---------------- standalone GEMMs (layers 2, 3) ----------------
template <int NOUT>
__global__ __launch_bounds__(256) void k_gemm_mfma(const float* __restrict__ X,
                                                   const ushort* __restrict__ Wt,
                                                   ushort* __restrict__ H, int N) {
    __shared__ char smem[64 * 256 + NOUT * 256];
    gemm_body<NOUT>(X, Wt, H, N, blockIdx.x, threadIdx.x, smem);
}

// ---------------- single-kernel scan: rp/rpe/cursor/dinv via atomic block base ----------------
__global__ void k_scan(const uint64* __restrict__ degcnt, int* __restrict__ rp,
                       int* __restrict__ rpe, int* __restrict__ cursor,
                       float* __restrict__ dinv, int* __restrict__ base_ctr, int n) {
    __shared__ int tsum[256];
    __shared__ int sbase;
    const int base = blockIdx.x * 1024;
    const int t = threadIdx.x;
    int v[4], s = 0;
    uint64 dc[4];
#pragma unroll
    for (int j = 0; j < 4; ++j) {
        int idx = base + t * 4 + j;
        dc[j] = (idx < n) ? degcnt[idx] : 0ull;
        v[j] = (int)(dc[j] >> 44);
        s += v[j];
    }
    tsum[t] = s;
    __syncthreads();
    for (int off = 1; off < 256; off <<= 1) {
        int x = (t >= off) ? tsum[t - off] : 0;
        __syncthreads();
        tsum[t] += x;
        __syncthreads();
    }
    if (t == 255) sbase = atomicAdd(base_ctr, tsum[255]);
    __syncthreads();
    int excl = sbase + ((t > 0) ? tsum[t - 1] : 0);
#pragma unroll
    for (int j = 0; j < 4; ++j) {
        int idx = base + t * 4 + j;
        if (idx < n) {
            rp[idx] = excl;
            rpe[idx] = excl + v[j];
            cursor[idx] = excl;
            float d = (float)(dc[j] & 0xFFFFFFFFFFFull) * (1.0f / 4294967296.0f);
            dinv[idx] = (d > 0.f) ? rsqrtf(d) : 0.f;
        }
        excl += v[j];
    }
}

// ---------------- fill CSR buckets: ep[pos] = (src, norm) ----------------
__global__ void k_fill(const int* __restrict__ src, const int* __restrict__ dst,
                       const float* __restrict__ ew, const float* __restrict__ dinv,
                       int* __restrict__ cursor, uint2* __restrict__ ep, int E) {
    int e = blockIdx.x * blockDim.x + threadIdx.x;
    if (e < E) {
        int s = src[e], d = dst[e];
        int pos = atomicAdd(&cursor[d], 1);
        float nv = dinv[s] * ew[e] * dinv[d];
        ep[pos] = make_uint2((uint32)s, __float_as_uint(nv));
    }
}

#define FMA8(aQ, hQ, w)                                   \
    aQ[0] = fmaf(w, bf2f(hQ.x & 0xffffu), aQ[0]);         \
    aQ[1] = fmaf(w, bf2f(hQ.x >> 16), aQ[1]);             \
    aQ[2] = fmaf(w, bf2f(hQ.y & 0xffffu), aQ[2]);         \
    aQ[3] = fmaf(w, bf2f(hQ.y >> 16), aQ[3]);             \
    aQ[4] = fmaf(w, bf2f(hQ.z & 0xffffu), aQ[4]);         \
    aQ[5] = fmaf(w, bf2f(hQ.z >> 16), aQ[5]);             \
    aQ[6] = fmaf(w, bf2f(hQ.w & 0xffffu), aQ[6]);         \
    aQ[7] = fmaf(w, bf2f(hQ.w >> 16), aQ[7])

// ---------------- aggregate (D=128): 4 nodes/wave x 4 edge-slots x 16 lanes ----------------
template <int RELU>
__global__ void k_agg128(const int* __restrict__ rp, const int* __restrict__ rpe,
                         const uint2* __restrict__ ep, const ushort* __restrict__ H,
                         const float* __restrict__ b, float* __restrict__ out, int N) {
    const int wave = threadIdx.x >> 6;
    const int lane = threadIdx.x & 63;
    const int n0 = blockIdx.x * 16 + wave * 4;
    if (n0 >= N) return;
    const int slot = lane >> 4;
    const int l16 = lane & 15;
    const uint4* H4 = reinterpret_cast<const uint4*>(H);

    const float4 b0 = *reinterpret_cast<const float4*>(&b[l16 * 8]);
    const float4 b1 = *reinterpret_cast<const float4*>(&b[l16 * 8 + 4]);

    int eA = 0, xA = 0, eB = 0, xB = 0, eC = 0, xC = 0, eD = 0, xD = 0;
    { int n = n0;     if (n < N) { eA = rp[n] + slot; xA = rpe[n]; } }
    { int n = n0 + 1; if (n < N) { eB = rp[n] + slot; xB = rpe[n]; } }
    { int n = n0 + 2; if (n < N) { eC = rp[n] + slot; xC = rpe[n]; } }
    { int n = n0 + 3; if (n < N) { eD = rp[n] + slot; xD = rpe[n]; } }

    float aA[8] = {}, aB[8] = {}, aC[8] = {}, aD[8] = {};
    bool vA = eA < xA, vB = eB < xB, vC = eC < xC, vD = eD < xD;
    uint2 pA, pB, pC, pD;
    if (vA) pA = ep[eA];
    if (vB) pB = ep[eB];
    if (vC) pC = ep[eC];
    if (vD) pD = ep[eD];
    while (vA || vB || vC || vD) {
        uint4 hA, hB, hC, hD;
        if (vA) hA = H4[(size_t)pA.x * 16 + l16];
        if (vB) hB = H4[(size_t)pB.x * 16 + l16];
        if (vC) hC = H4[(size_t)pC.x * 16 + l16];
        if (vD) hD = H4[(size_t)pD.x * 16 + l16];
        const bool nA2 = (eA + 4) < xA, nB2 = (eB + 4) < xB;
        const bool nC2 = (eC + 4) < xC, nD2 = (eD + 4) < xD;
        uint2 qA, qB, qC, qD;
        if (nA2) qA = ep[eA + 4];
        if (nB2) qB = ep[eB + 4];
        if (nC2) qC = ep[eC + 4];
        if (nD2) qD = ep[eD + 4];
        if (vA) { float w = __uint_as_float(pA.y); FMA8(aA, hA, w); }
        if (vB) { float w = __uint_as_float(pB.y); FMA8(aB, hB, w); }
        if (vC) { float w = __uint_as_float(pC.y); FMA8(aC, hC, w); }
        if (vD) { float w = __uint_as_float(pD.y); FMA8(aD, hD, w); }
        eA += 4; eB += 4; eC += 4; eD += 4;
        vA = nA2; vB = nB2; vC = nC2; vD = nD2;
        pA = qA; pB = qB; pC = qC; pD = qD;
    }
#pragma unroll
    for (int j = 0; j < 8; ++j) {
        aA[j] += __shfl_xor(aA[j], 32); aA[j] += __shfl_xor(aA[j], 16);
        aB[j] += __shfl_xor(aB[j], 32); aB[j] += __shfl_xor(aB[j], 16);
        aC[j] += __shfl_xor(aC[j], 32); aC[j] += __shfl_xor(aC[j], 16);
        aD[j] += __shfl_xor(aD[j], 32); aD[j] += __shfl_xor(aD[j], 16);
    }
    const int nq = n0 + (lane >> 4);
    if (nq < N) {
        float o[8];
        if (lane < 16) {
#pragma unroll
            for (int j = 0; j < 8; ++j) o[j] = aA[j];
        } else if (lane < 32) {
#pragma unroll
            for (int j = 0; j < 8; ++j) o[j] = aB[j];
        } else if (lane < 48) {
#pragma unroll
            for (int j = 0; j < 8; ++j) o[j] = aC[j];
        } else {
#pragma unroll
            for (int j = 0; j < 8; ++j) o[j] = aD[j];
        }
        float4 o0 = make_float4(o[0] + b0.x, o[1] + b0.y, o[2] + b0.z, o[3] + b0.w);
        float4 o1 = make_float4(o[4] + b1.x, o[5] + b1.y, o[6] + b1.z, o[7] + b1.w);
        if (RELU) {
            o0.x = fmaxf(o0.x, 0.f); o0.y = fmaxf(o0.y, 0.f);
            o0.z = fmaxf(o0.z, 0.f); o0.w = fmaxf(o0.w, 0.f);
            o1.x = fmaxf(o1.x, 0.f); o1.y = fmaxf(o1.y, 0.f);
            o1.z = fmaxf(o1.z, 0.f); o1.w = fmaxf(o1.w, 0.f);
        }
        float* op = &out[(size_t)nq * 128 + l16 * 8];
        *reinterpret_cast<float4*>(op) = o0;
        *reinterpret_cast<float4*>(op + 4) = o1;
    }
}

// ---------------- aggregate (D=64): 4 nodes/wave x 8 edge-slots x 8 lanes ----------------
template <int RELU>
__global__ void k_agg64(const int* __restrict__ rp, const int* __restrict__ rpe,
                        const uint2* __restrict__ ep, const ushort* __restrict__ H,
                        const float* __restrict__ b, float* __restrict__ out, int N) {
    const int wave = threadIdx.x >> 6;
    const int lane = threadIdx.x & 63;
    const int n0 = blockIdx.x * 16 + wave * 4;
    if (n0 >= N) return;
    const int slot = lane >> 3;
    const int l8 = lane & 7;
    const uint4* H4 = reinterpret_cast<const uint4*>(H);

    const float4 b0 = *reinterpret_cast<const float4*>(&b[l8 * 8]);
    const float4 b1 = *reinterpret_cast<const float4*>(&b[l8 * 8 + 4]);

    int eA = 0, xA = 0, eB = 0, xB = 0, eC = 0, xC = 0, eD = 0, xD = 0;
    { int n = n0;     if (n < N) { eA = rp[n] + slot; xA = rpe[n]; } }
    { int n = n0 + 1; if (n < N) { eB = rp[n] + slot; xB = rpe[n]; } }
    { int n = n0 + 2; if (n < N) { eC = rp[n] + slot; xC = rpe[n]; } }
    { int n = n0 + 3; if (n < N) { eD = rp[n] + slot; xD = rpe[n]; } }

    float aA[8] = {}, aB[8] = {}, aC[8] = {}, aD[8] = {};
    bool vA = eA < xA, vB = eB < xB, vC = eC < xC, vD = eD < xD;
    uint2 pA, pB, pC, pD;
    if (vA) pA = ep[eA];
    if (vB) pB = ep[eB];
    if (vC) pC = ep[eC];
    if (vD) pD = ep[eD];
    while (vA || vB || vC || vD) {
        uint4 hA, hB, hC, hD;
        if (vA) hA = H4[(size_t)pA.x * 8 + l8];
        if (vB) hB = H4[(size_t)pB.x * 8 + l8];
        if (vC) hC = H4[(size_t)pC.x * 8 + l8];
        if (vD) hD = H4[(size_t)pD.x * 8 + l8];
        const bool nA2 = (eA + 8) < xA, nB2 = (eB + 8) < xB;
        const bool nC2 = (eC + 8) < xC, nD2 = (eD + 8) < xD;
        uint2 qA, qB, qC, qD;
        if (nA2) qA = ep[eA + 8];
        if (nB2) qB = ep[eB + 8];
        if (nC2) qC = ep[eC + 8];
        if (nD2) qD = ep[eD + 8];
        if (vA) { float w = __uint_as_float(pA.y); FMA8(aA, hA, w); }
        if (vB) { float w = __uint_as_float(pB.y); FMA8(aB, hB, w); }
        if (vC) { float w = __uint_as_float(pC.y); FMA8(aC, hC, w); }
        if (vD) { float w = __uint_as_float(pD.y); FMA8(aD, hD, w); }
        eA += 8; eB += 8; eC += 8; eD += 8;
        vA = nA2; vB = nB2; vC = nC2; vD = nD2;
        pA = qA; pB = qB; pC = qC; pD = qD;
    }
#pragma unroll
    for (int j = 0; j < 8; ++j) {
        aA[j] += __shfl_xor(aA[j], 8); aA[j] += __shfl_xor(aA[j], 16); aA[j] += __shfl_xor(aA[j], 32);
        aB[j] += __shfl_xor(aB[j], 8); aB[j] += __shfl_xor(aB[j], 16); aB[j] += __shfl_xor(aB[j], 32);
        aC[j] += __shfl_xor(aC[j], 8); aC[j] += __shfl_xor(aC[j], 16); aC[j] += __shfl_xor(aC[j], 32);
        aD[j] += __shfl_xor(aD[j], 8); aD[j] += __shfl_xor(aD[j], 16); aD[j] += __shfl_xor(aD[j], 32);
    }
    const int nq = n0 + (lane >> 3);
    if (lane < 32 && nq < N) {
        float o[8];
        if (lane < 8) {
#pragma unroll
            for (int j = 0; j < 8; ++j) o[j] = aA[j];
        } else if (lane < 16) {
#pragma unroll
            for (int j = 0; j < 8; ++j) o[j] = aB[j];
        } else if (lane < 24) {
#pragma unroll
            for (int j = 0; j < 8; ++j) o[j] = aC[j];
        } else {
#pragma unroll
            for (int j = 0; j < 8; ++j) o[j] = aD[j];
        }
        float4 o0 = make_float4(o[0] + b0.x, o[1] + b0.y, o[2] + b0.z, o[3] + b0.w);
        float4 o1 = make_float4(o[4] + b1.x, o[5] + b1.y, o[6] + b1.z, o[7] + b1.w);
        if (RELU) {
            o0.x = fmaxf(o0.x, 0.f); o0.y = fmaxf(o0.y, 0.f);
            o0.z = fmaxf(o0.z, 0.f); o0.w = fmaxf(o0.w, 0.f);
            o1.x = fmaxf(o1.x, 0.f); o1.y = fmaxf(o1.y, 0.f);
            o1.z = fmaxf(o1.z, 0.f); o1.w = fmaxf(o1.w, 0.f);
        }
        float* op = &out[(size_t)nq * 64 + l8 * 8];
        *reinterpret_cast<float4*>(op) = o0;
        *reinterpret_cast<float4*>(op + 4) = o1;
    }
}

// ---------------- launch ----------------

extern "C" void kernel_launch(void* const* d_in, const int* in_sizes, int n_in,
                              void* d_out, int out_size, void* d_ws, size_t ws_size,
                              hipStream_t stream) {
    const float* x  = (const float*)d_in[0];
    const int*   ei = (const int*)d_in[1];
    const float* ew = (const float*)d_in[2];
    const float* W1 = (const float*)d_in[3];
    const float* b1 = (const float*)d_in[4];
    const float* W2 = (const float*)d_in[5];
    const float* b2 = (const float*)d_in[6];
    const float* W3 = (const float*)d_in[7];
    const float* b3 = (const float*)d_in[8];

    const int* src = ei;
    const int* dst = ei + NE;

    // ws layout (~58 MB)
    float*  ws       = (float*)d_ws;
    uint64* degcnt   = (uint64*)ws;                  // NN u64 = 2NN ints
    int*    base_ctr = (int*)(ws + 2 * NN);          // 1 int (zeroed with degcnt)
    int*    rp       = (int*)(ws + 2 * NN + 64);     // NN i
    int*    rpe      = (int*)(ws + 3 * NN + 64);     // NN i
    uint2*  ep       = (uint2*)(ws + 4 * NN + 128);  // NE uint2
    ushort* h1       = (ushort*)(ws + 4 * NN + 128 + 2 * NE); // NN*128 bf16
    ushort* h2       = h1 + (size_t)NN * 128;                 // NN*128 bf16
    ushort* h3       = h1;                                    // NN*64 bf16 (aliases h1)
    ushort* wt1      = h2 + (size_t)NN * 128;        // 128*128 bf16
    ushort* wt2      = wt1 + 128 * 128;              // 128*128 bf16
    ushort* wt3      = wt2 + 128 * 128;              // 64*128 bf16
    int*    cursor   = (int*)h2;                     // NN i (aliases h2; dead before gemm2)

    float* out0 = (float*)d_out;                     // [NN,128]
    float* out1 = out0 + NN * 128;                   // [NN,128]
    float* out2 = out1 + NN * 128;                   // [NN,64]
    float* dinv = out2;                              // NN f scratch (dead until agg64)

    const int B = 256;
    const int NB_SCAN = (NN + 1023) / 1024;          // 98
    const int AGB = (NN + 15) / 16;                  // 6250 agg blocks (16 nodes each)

    // prepW + zero degcnt/base_ctr (one kernel)
    k_prep_zero<<<PWB + ZB, B, 0, stream>>>(W1, W2, W3, wt1, wt2, wt3, (int*)degcnt);

    // merged: layer-1 GEMM; each block appends its 410-edge packed-histogram tail
    k_gemm1_hist<<<GB1, 256, 0, stream>>>(x, wt1, h1, NN, dst, ew, degcnt);

    // single-kernel scan (rp/rpe/cursor/dinv)
    k_scan<<<NB_SCAN, 256, 0, stream>>>(degcnt, rp, rpe, cursor, dinv, base_ctr, NN);
    k_fill<<<(NE + B - 1) / B, B, 0, stream>>>(src, dst, ew, dinv, cursor, ep, NE);

    // ----- layer 1 aggregate -----
    k_agg128<1><<<AGB, 256, 0, stream>>>(rp, rpe, ep, h1, b1, out0, NN);

    // ----- layer 2 -----
    k_gemm_mfma<128><<<GB1, 256, 0, stream>>>(out0, wt2, h2, NN);
    k_agg128<1><<<AGB, 256, 0, stream>>>(rp, rpe, ep, h2, b2, out1, NN);

    // ----- layer 3 -----
    k_gemm_mfma<64><<<GB1, 256, 0, stream>>>(out1, wt3, h3, NN);
    k_agg64<0><<<AGB, 256, 0, stream>>>(rp, rpe, ep, h3, b3, out2, NN);
}

// Round 18
// 224.081 us; speedup vs baseline: 1.1569x; 1.1569x over previous
//
#include <hip/hip_runtime.h>

#define NN 100000
#define NE 640000
#define GB1 ((NN + 63) / 64)        // 1563 gemm blocks (64 rows each)
#define EPB ((NE + GB1 - 1) / GB1)  // 410 edges per gemm block (hist tail)
#define PWB 160                     // prepW blocks (40960 elems / 256)
#define ZB  ((2 * NN + 64 + 255) / 256) // zero blocks (degcnt + base_ctr pad)

typedef unsigned int uint32;
typedef unsigned long long uint64;
typedef __attribute__((ext_vector_type(8))) short short8;
typedef __attribute__((ext_vector_type(4))) float f32x4;

static __device__ __forceinline__ ushort f2bf(float f) {
    uint32 u = __float_as_uint(f);
    u = (u + 0x7fffu + ((u >> 16) & 1u)) >> 16;
    return (ushort)u;
}
static __device__ __forceinline__ float bf2f(uint32 bits16) {
    return __uint_as_float(bits16 << 16);
}
static __device__ __forceinline__ uint32 pack2(float a, float b) {
    return (uint32)f2bf(a) | ((uint32)f2bf(b) << 16);
}

// ---------------- prepW (blocks 0..159) + zero degcnt/base_ctr (blocks 160+) ----------------
__global__ void k_prep_zero(const float* __restrict__ W1, const float* __restrict__ W2,
                            const float* __restrict__ W3, ushort* __restrict__ wt1,
                            ushort* __restrict__ wt2, ushort* __restrict__ wt3,
                            int* __restrict__ zbase) {
    const int b = blockIdx.x;
    if (b < PWB) {
        int o = b * 256 + threadIdx.x;
        if (o < 16384) {
            int col = o >> 7, k = o & 127;
            wt1[o] = f2bf(W1[k * 128 + col]);
        } else if (o < 32768) {
            int oo = o - 16384;
            int col = oo >> 7, k = oo & 127;
            wt2[oo] = f2bf(W2[k * 128 + col]);
        } else if (o < 40960) {
            int oo = o - 32768;
            int col = oo >> 7, k = oo & 127;
            wt3[oo] = f2bf(W3[k * 64 + col]);
        }
    } else {
        int i = (b - PWB) * 256 + threadIdx.x;
        if (i < 2 * NN + 64) zbase[i] = 0;   // degcnt (2NN ints) + base_ctr pad
    }
}

// ---------------- GEMM body (R11-proven): H(bf16) = X(f32->bf16) @ Wt(bf16) ----------------
template <int NOUT>
static __device__ __forceinline__ void gemm_body(const float* __restrict__ X,
                                                 const ushort* __restrict__ Wt,
                                                 ushort* __restrict__ H, int N,
                                                 int bid, int tid, char* smem) {
    char* xs = smem;              // [64 rows][128 k] bf16, swizzled
    char* wt = smem + 64 * 256;   // [NOUT cols][128 k] bf16, swizzled
    const int row0 = bid * 64;

    const uint4* Wt4 = reinterpret_cast<const uint4*>(Wt);
#pragma unroll
    for (int i = 0; i < NOUT / 16; ++i) {
        int id = tid + 256 * i;
        int col = id >> 4, c4 = id & 15;
        uint4 v = Wt4[id];
        *reinterpret_cast<uint4*>(wt + col * 256 + ((c4 * 16) ^ ((col & 7) << 4))) = v;
    }
#pragma unroll
    for (int i = 0; i < 8; ++i) {
        int id = tid + 256 * i;
        int r = id >> 5, c4 = id & 31;
        int gr = row0 + r;
        float4 v = make_float4(0.f, 0.f, 0.f, 0.f);
        if (gr < N) v = *reinterpret_cast<const float4*>(&X[(size_t)gr * 128 + c4 * 4]);
        uint2 pk;
        pk.x = pack2(v.x, v.y);
        pk.y = pack2(v.z, v.w);
        *reinterpret_cast<uint2*>(xs + r * 256 + ((c4 * 8) ^ ((r & 7) << 4))) = pk;
    }
    __syncthreads();

    const int w = tid >> 6, lane = tid & 63;
    const int rl = w * 16 + (lane & 15);
    const int kg = lane >> 4;
    f32x4 acc[NOUT / 16];
#pragma unroll
    for (int ct = 0; ct < NOUT / 16; ++ct) acc[ct] = (f32x4){0.f, 0.f, 0.f, 0.f};

#pragma unroll
    for (int ks = 0; ks < 4; ++ks) {
        const int kb = ks * 64 + kg * 16;
        short8 a = *reinterpret_cast<const short8*>(xs + rl * 256 + (kb ^ ((rl & 7) << 4)));
#pragma unroll
        for (int ct = 0; ct < NOUT / 16; ++ct) {
            int col = ct * 16 + (lane & 15);
            short8 bfr = *reinterpret_cast<const short8*>(wt + col * 256 + (kb ^ ((col & 7) << 4)));
            acc[ct] = __builtin_amdgcn_mfma_f32_16x16x32_bf16(a, bfr, acc[ct], 0, 0, 0);
        }
    }
    // C/D layout: col=lane&15, row=(lane>>4)*4+reg (m89-verified)
#pragma unroll
    for (int ct = 0; ct < NOUT / 16; ++ct) {
        int col = ct * 16 + (lane & 15);
#pragma unroll
        for (int r = 0; r < 4; ++r) {
            int gr = row0 + w * 16 + (lane >> 4) * 4 + r;
            if (gr < N) H[(size_t)gr * NOUT + col] = f2bf(acc[ct][r]);
        }
    }
}

// ---------------- merged: gemm1 + per-block hist tail (packed u64 atomic) ----------------
__global__ __launch_bounds__(256) void k_gemm1_hist(const float* __restrict__ X,
                                                    const ushort* __restrict__ Wt1,
                                                    ushort* __restrict__ H, int N,
                                                    const int* __restrict__ dst,
                                                    const float* __restrict__ ew,
                                                    uint64* __restrict__ degcnt) {
    __shared__ char smem[64 * 256 + 128 * 256];
    gemm_body<128>(X, Wt1, H, N, blockIdx.x, threadIdx.x, smem);
    const int ebase = blockIdx.x * EPB;
    const int eend = (ebase + EPB < NE) ? ebase + EPB : NE;
    for (int e = ebase + threadIdx.x; e < eend; e += 256) {
        uint64 pk = (1ull << 44) | (uint64)(ew[e] * 4294967296.0f);
        atomicAdd(&degcnt[dst[e]], pk);
    }
}

// ---------------- standalone GEMMs (layers 2, 3) ----------------
template <int NOUT>
__global__ __launch_bounds__(256) void k_gemm_mfma(const float* __restrict__ X,
                                                   const ushort* __restrict__ Wt,
                                                   ushort* __restrict__ H, int N) {
    __shared__ char smem[64 * 256 + NOUT * 256];
    gemm_body<NOUT>(X, Wt, H, N, blockIdx.x, threadIdx.x, smem);
}

// ---------------- single-kernel scan: rp/rpe/cursor/dinv via atomic block base ----------------
__global__ void k_scan(const uint64* __restrict__ degcnt, int* __restrict__ rp,
                       int* __restrict__ rpe, int* __restrict__ cursor,
                       float* __restrict__ dinv, int* __restrict__ base_ctr, int n) {
    __shared__ int tsum[256];
    __shared__ int sbase;
    const int base = blockIdx.x * 1024;
    const int t = threadIdx.x;
    int v[4], s = 0;
    uint64 dc[4];
#pragma unroll
    for (int j = 0; j < 4; ++j) {
        int idx = base + t * 4 + j;
        dc[j] = (idx < n) ? degcnt[idx] : 0ull;
        v[j] = (int)(dc[j] >> 44);
        s += v[j];
    }
    tsum[t] = s;
    __syncthreads();
    for (int off = 1; off < 256; off <<= 1) {
        int x = (t >= off) ? tsum[t - off] : 0;
        __syncthreads();
        tsum[t] += x;
        __syncthreads();
    }
    if (t == 255) sbase = atomicAdd(base_ctr, tsum[255]);
    __syncthreads();
    int excl = sbase + ((t > 0) ? tsum[t - 1] : 0);
#pragma unroll
    for (int j = 0; j < 4; ++j) {
        int idx = base + t * 4 + j;
        if (idx < n) {
            rp[idx] = excl;
            rpe[idx] = excl + v[j];
            cursor[idx] = excl;
            float d = (float)(dc[j] & 0xFFFFFFFFFFFull) * (1.0f / 4294967296.0f);
            dinv[idx] = (d > 0.f) ? rsqrtf(d) : 0.f;
        }
        excl += v[j];
    }
}

// ---------------- fill CSR buckets: ep[pos] = (src, norm) ----------------
__global__ void k_fill(const int* __restrict__ src, const int* __restrict__ dst,
                       const float* __restrict__ ew, const float* __restrict__ dinv,
                       int* __restrict__ cursor, uint2* __restrict__ ep, int E) {
    int e = blockIdx.x * blockDim.x + threadIdx.x;
    if (e < E) {
        int s = src[e], d = dst[e];
        int pos = atomicAdd(&cursor[d], 1);
        float nv = dinv[s] * ew[e] * dinv[d];
        ep[pos] = make_uint2((uint32)s, __float_as_uint(nv));
    }
}

// ---------------- aggregate (D=128): 2 nodes/wave x 4 edge-slots x 16 lanes ----------------
template <int RELU>
__global__ void k_agg128(const int* __restrict__ rp, const int* __restrict__ rpe,
                         const uint2* __restrict__ ep, const ushort* __restrict__ H,
                         const float* __restrict__ b, float* __restrict__ out, int N) {
    const int wave = threadIdx.x >> 6;
    const int lane = threadIdx.x & 63;
    const int nA = blockIdx.x * 8 + wave * 2;
    const int nB = nA + 1;
    if (nA >= N) return;
    const int slot = lane >> 4;
    const int l16 = lane & 15;
    const uint4* H4 = reinterpret_cast<const uint4*>(H);

    const float4 b0 = *reinterpret_cast<const float4*>(&b[l16 * 8]);
    const float4 b1 = *reinterpret_cast<const float4*>(&b[l16 * 8 + 4]);

    int eA = rp[nA] + slot, e1A = rpe[nA];
    int eB = 0, e1B = 0;
    if (nB < N) { eB = rp[nB] + slot; e1B = rpe[nB]; }

    float aA[8] = {}, aB[8] = {};
    bool vA = eA < e1A, vB = eB < e1B;
    uint2 pA, pB;
    if (vA) pA = ep[eA];
    if (vB) pB = ep[eB];
    while (vA || vB) {
        uint4 hA, hB;
        if (vA) hA = H4[(size_t)pA.x * 16 + l16];
        if (vB) hB = H4[(size_t)pB.x * 16 + l16];
        const bool vnA = (eA + 4) < e1A, vnB = (eB + 4) < e1B;
        uint2 pnA, pnB;
        if (vnA) pnA = ep[eA + 4];
        if (vnB) pnB = ep[eB + 4];
        if (vA) {
            float w = __uint_as_float(pA.y);
            aA[0] = fmaf(w, bf2f(hA.x & 0xffffu), aA[0]);
            aA[1] = fmaf(w, bf2f(hA.x >> 16), aA[1]);
            aA[2] = fmaf(w, bf2f(hA.y & 0xffffu), aA[2]);
            aA[3] = fmaf(w, bf2f(hA.y >> 16), aA[3]);
            aA[4] = fmaf(w, bf2f(hA.z & 0xffffu), aA[4]);
            aA[5] = fmaf(w, bf2f(hA.z >> 16), aA[5]);
            aA[6] = fmaf(w, bf2f(hA.w & 0xffffu), aA[6]);
            aA[7] = fmaf(w, bf2f(hA.w >> 16), aA[7]);
        }
        if (vB) {
            float w = __uint_as_float(pB.y);
            aB[0] = fmaf(w, bf2f(hB.x & 0xffffu), aB[0]);
            aB[1] = fmaf(w, bf2f(hB.x >> 16), aB[1]);
            aB[2] = fmaf(w, bf2f(hB.y & 0xffffu), aB[2]);
            aB[3] = fmaf(w, bf2f(hB.y >> 16), aB[3]);
            aB[4] = fmaf(w, bf2f(hB.z & 0xffffu), aB[4]);
            aB[5] = fmaf(w, bf2f(hB.z >> 16), aB[5]);
            aB[6] = fmaf(w, bf2f(hB.w & 0xffffu), aB[6]);
            aB[7] = fmaf(w, bf2f(hB.w >> 16), aB[7]);
        }
        eA += 4; eB += 4;
        vA = vnA; vB = vnB;
        pA = pnA; pB = pnB;
    }
#pragma unroll
    for (int j = 0; j < 8; ++j) {
        aA[j] += __shfl_xor(aA[j], 32);
        aA[j] += __shfl_xor(aA[j], 16);
        aB[j] += __shfl_xor(aB[j], 32);
        aB[j] += __shfl_xor(aB[j], 16);
    }
    if (lane < 16) {
        float4 o0 = make_float4(aA[0] + b0.x, aA[1] + b0.y, aA[2] + b0.z, aA[3] + b0.w);
        float4 o1 = make_float4(aA[4] + b1.x, aA[5] + b1.y, aA[6] + b1.z, aA[7] + b1.w);
        if (RELU) {
            o0.x = fmaxf(o0.x, 0.f); o0.y = fmaxf(o0.y, 0.f);
            o0.z = fmaxf(o0.z, 0.f); o0.w = fmaxf(o0.w, 0.f);
            o1.x = fmaxf(o1.x, 0.f); o1.y = fmaxf(o1.y, 0.f);
            o1.z = fmaxf(o1.z, 0.f); o1.w = fmaxf(o1.w, 0.f);
        }
        float* op = &out[(size_t)nA * 128 + l16 * 8];
        *reinterpret_cast<float4*>(op) = o0;
        *reinterpret_cast<float4*>(op + 4) = o1;
    } else if (lane < 32 && nB < N) {
        float4 o0 = make_float4(aB[0] + b0.x, aB[1] + b0.y, aB[2] + b0.z, aB[3] + b0.w);
        float4 o1 = make_float4(aB[4] + b1.x, aB[5] + b1.y, aB[6] + b1.z, aB[7] + b1.w);
        if (RELU) {
            o0.x = fmaxf(o0.x, 0.f); o0.y = fmaxf(o0.y, 0.f);
            o0.z = fmaxf(o0.z, 0.f); o0.w = fmaxf(o0.w, 0.f);
            o1.x = fmaxf(o1.x, 0.f); o1.y = fmaxf(o1.y, 0.f);
            o1.z = fmaxf(o1.z, 0.f); o1.w = fmaxf(o1.w, 0.f);
        }
        float* op = &out[(size_t)nB * 128 + l16 * 8];
        *reinterpret_cast<float4*>(op) = o0;
        *reinterpret_cast<float4*>(op + 4) = o1;
    }
}

// ---------------- aggregate (D=64): 2 nodes/wave x 8 edge-slots x 8 lanes ----------------
template <int RELU>
__global__ void k_agg64(const int* __restrict__ rp, const int* __restrict__ rpe,
                        const uint2* __restrict__ ep, const ushort* __restrict__ H,
                        const float* __restrict__ b, float* __restrict__ out, int N) {
    const int wave = threadIdx.x >> 6;
    const int lane = threadIdx.x & 63;
    const int nA = blockIdx.x * 8 + wave * 2;
    const int nB = nA + 1;
    if (nA >= N) return;
    const int slot = lane >> 3;
    const int l8 = lane & 7;
    const uint4* H4 = reinterpret_cast<const uint4*>(H);

    const float4 b0 = *reinterpret_cast<const float4*>(&b[l8 * 8]);
    const float4 b1 = *reinterpret_cast<const float4*>(&b[l8 * 8 + 4]);

    int eA = rp[nA] + slot, e1A = rpe[nA];
    int eB = 0, e1B = 0;
    if (nB < N) { eB = rp[nB] + slot; e1B = rpe[nB]; }

    float aA[8] = {}, aB[8] = {};
    bool vA = eA < e1A, vB = eB < e1B;
    uint2 pA, pB;
    if (vA) pA = ep[eA];
    if (vB) pB = ep[eB];
    while (vA || vB) {
        uint4 hA, hB;
        if (vA) hA = H4[(size_t)pA.x * 8 + l8];
        if (vB) hB = H4[(size_t)pB.x * 8 + l8];
        const bool vnA = (eA + 8) < e1A, vnB = (eB + 8) < e1B;
        uint2 pnA, pnB;
        if (vnA) pnA = ep[eA + 8];
        if (vnB) pnB = ep[eB + 8];
        if (vA) {
            float w = __uint_as_float(pA.y);
            aA[0] = fmaf(w, bf2f(hA.x & 0xffffu), aA[0]);
            aA[1] = fmaf(w, bf2f(hA.x >> 16), aA[1]);
            aA[2] = fmaf(w, bf2f(hA.y & 0xffffu), aA[2]);
            aA[3] = fmaf(w, bf2f(hA.y >> 16), aA[3]);
            aA[4] = fmaf(w, bf2f(hA.z & 0xffffu), aA[4]);
            aA[5] = fmaf(w, bf2f(hA.z >> 16), aA[5]);
            aA[6] = fmaf(w, bf2f(hA.w & 0xffffu), aA[6]);
            aA[7] = fmaf(w, bf2f(hA.w >> 16), aA[7]);
        }
        if (vB) {
            float w = __uint_as_float(pB.y);
            aB[0] = fmaf(w, bf2f(hB.x & 0xffffu), aB[0]);
            aB[1] = fmaf(w, bf2f(hB.x >> 16), aB[1]);
            aB[2] = fmaf(w, bf2f(hB.y & 0xffffu), aB[2]);
            aB[3] = fmaf(w, bf2f(hB.y >> 16), aB[3]);
            aB[4] = fmaf(w, bf2f(hB.z & 0xffffu), aB[4]);
            aB[5] = fmaf(w, bf2f(hB.z >> 16), aB[5]);
            aB[6] = fmaf(w, bf2f(hB.w & 0xffffu), aB[6]);
            aB[7] = fmaf(w, bf2f(hB.w >> 16), aB[7]);
        }
        eA += 8; eB += 8;
        vA = vnA; vB = vnB;
        pA = pnA; pB = pnB;
    }
#pragma unroll
    for (int j = 0; j < 8; ++j) {
        aA[j] += __shfl_xor(aA[j], 8);
        aA[j] += __shfl_xor(aA[j], 16);
        aA[j] += __shfl_xor(aA[j], 32);
        aB[j] += __shfl_xor(aB[j], 8);
        aB[j] += __shfl_xor(aB[j], 16);
        aB[j] += __shfl_xor(aB[j], 32);
    }
    if (lane < 8) {
        float4 o0 = make_float4(aA[0] + b0.x, aA[1] + b0.y, aA[2] + b0.z, aA[3] + b0.w);
        float4 o1 = make_float4(aA[4] + b1.x, aA[5] + b1.y, aA[6] + b1.z, aA[7] + b1.w);
        if (RELU) {
            o0.x = fmaxf(o0.x, 0.f); o0.y = fmaxf(o0.y, 0.f);
            o0.z = fmaxf(o0.z, 0.f); o0.w = fmaxf(o0.w, 0.f);
            o1.x = fmaxf(o1.x, 0.f); o1.y = fmaxf(o1.y, 0.f);
            o1.z = fmaxf(o1.z, 0.f); o1.w = fmaxf(o1.w, 0.f);
        }
        float* op = &out[(size_t)nA * 64 + l8 * 8];
        *reinterpret_cast<float4*>(op) = o0;
        *reinterpret_cast<float4*>(op + 4) = o1;
    } else if (lane < 16 && nB < N) {
        float4 o0 = make_float4(aB[0] + b0.x, aB[1] + b0.y, aB[2] + b0.z, aB[3] + b0.w);
        float4 o1 = make_float4(aB[4] + b1.x, aB[5] + b1.y, aB[6] + b1.z, aB[7] + b1.w);
        if (RELU) {
            o0.x = fmaxf(o0.x, 0.f); o0.y = fmaxf(o0.y, 0.f);
            o0.z = fmaxf(o0.z, 0.f); o0.w = fmaxf(o0.w, 0.f);
            o1.x = fmaxf(o1.x, 0.f); o1.y = fmaxf(o1.y, 0.f);
            o1.z = fmaxf(o1.z, 0.f); o1.w = fmaxf(o1.w, 0.f);
        }
        float* op = &out[(size_t)nB * 64 + l8 * 8];
        *reinterpret_cast<float4*>(op) = o0;
        *reinterpret_cast<float4*>(op + 4) = o1;
    }
}

// ---------------- launch ----------------

extern "C" void kernel_launch(void* const* d_in, const int* in_sizes, int n_in,
                              void* d_out, int out_size, void* d_ws, size_t ws_size,
                              hipStream_t stream) {
    const float* x  = (const float*)d_in[0];
    const int*   ei = (const int*)d_in[1];
    const float* ew = (const float*)d_in[2];
    const float* W1 = (const float*)d_in[3];
    const float* b1 = (const float*)d_in[4];
    const float* W2 = (const float*)d_in[5];
    const float* b2 = (const float*)d_in[6];
    const float* W3 = (const float*)d_in[7];
    const float* b3 = (const float*)d_in[8];

    const int* src = ei;
    const int* dst = ei + NE;

    // ws layout (~58 MB)
    float*  ws       = (float*)d_ws;
    uint64* degcnt   = (uint64*)ws;                  // NN u64 = 2NN ints
    int*    base_ctr = (int*)(ws + 2 * NN);          // 1 int (zeroed with degcnt)
    int*    rp       = (int*)(ws + 2 * NN + 64);     // NN i
    int*    rpe      = (int*)(ws + 3 * NN + 64);     // NN i
    uint2*  ep       = (uint2*)(ws + 4 * NN + 128);  // NE uint2
    ushort* h1       = (ushort*)(ws + 4 * NN + 128 + 2 * NE); // NN*128 bf16
    ushort* h2       = h1 + (size_t)NN * 128;                 // NN*128 bf16
    ushort* h3       = h1;                                    // NN*64 bf16 (aliases h1)
    ushort* wt1      = h2 + (size_t)NN * 128;        // 128*128 bf16
    ushort* wt2      = wt1 + 128 * 128;              // 128*128 bf16
    ushort* wt3      = wt2 + 128 * 128;              // 64*128 bf16
    int*    cursor   = (int*)h2;                     // NN i (aliases h2; dead before gemm2)

    float* out0 = (float*)d_out;                     // [NN,128]
    float* out1 = out0 + NN * 128;                   // [NN,128]
    float* out2 = out1 + NN * 128;                   // [NN,64]
    float* dinv = out2;                              // NN f scratch (dead until agg64)

    const int B = 256;
    const int NB_SCAN = (NN + 1023) / 1024;          // 98
    const int AGB = (NN + 7) / 8;                    // 12500 agg blocks (8 nodes each)

    // prepW + zero degcnt/base_ctr (one kernel)
    k_prep_zero<<<PWB + ZB, B, 0, stream>>>(W1, W2, W3, wt1, wt2, wt3, (int*)degcnt);

    // merged: layer-1 GEMM; each block appends its 410-edge packed-histogram tail
    k_gemm1_hist<<<GB1, 256, 0, stream>>>(x, wt1, h1, NN, dst, ew, degcnt);

    // single-kernel scan (rp/rpe/cursor/dinv)
    k_scan<<<NB_SCAN, 256, 0, stream>>>(degcnt, rp, rpe, cursor, dinv, base_ctr, NN);
    k_fill<<<(NE + B - 1) / B, B, 0, stream>>>(src, dst, ew, dinv, cursor, ep, NE);

    // ----- layer 1 aggregate -----
    k_agg128<1><<<AGB, 256, 0, stream>>>(rp, rpe, ep, h1, b1, out0, NN);

    // ----- layer 2 -----
    k_gemm_mfma<128><<<GB1, 256, 0, stream>>>(out0, wt2, h2, NN);
    k_agg128<1><<<AGB, 256, 0, stream>>>(rp, rpe, ep, h2, b2, out1, NN);

    // ----- layer 3 -----
    k_gemm_mfma<64><<<GB1, 256, 0, stream>>>(out1, wt3, h3, NN);
    k_agg64<0><<<AGB, 256, 0, stream>>>(rp, rpe, ep, h3, b3, out2, NN);
}